// Round 15
// baseline (221.105 us; speedup 1.0000x reference)
//
#include <hip/hip_runtime.h>
#include <hip/hip_bf16.h>
#include <math.h>
#include <stdint.h>

#define S_LEN 2048
#define D_DIM 128

typedef _Float16 f16x8 __attribute__((ext_vector_type(8)));
typedef __fp16  fp16x2 __attribute__((ext_vector_type(2)));   // cvt_pkrtz return type
typedef short bf8_t __attribute__((ext_vector_type(8)));
typedef float f32x4 __attribute__((ext_vector_type(4)));
typedef float f32x16 __attribute__((ext_vector_type(16)));
typedef unsigned int uint32x2 __attribute__((ext_vector_type(2)));
typedef _Float16 f16_t;

__device__ __forceinline__ short f2bf(float f) {
    union { float f; unsigned u; } x; x.f = f;
    unsigned u = x.u;
    u += 0x7FFF + ((u >> 16) & 1);
    return (short)(u >> 16);
}
__device__ __forceinline__ float bf2f(short h) {
    union { unsigned u; float f; } x;
    x.u = ((unsigned)(unsigned short)h) << 16;
    return x.f;
}
__device__ __forceinline__ uint32_t pkf16(float a, float b) {
    union { fp16x2 h; uint32_t u; } x;
    x.h = __builtin_amdgcn_cvt_pkrtz(a, b);
    return x.u;
}
__device__ __forceinline__ uint32x2 plswap(uint32_t a, uint32_t b) {
    return __builtin_amdgcn_permlane32_swap(a, b, false, false);
}
// bare v_exp_f32: computes 2^x in one instruction
__device__ __forceinline__ float exp2_fast(float x) {
    float r;
    asm("v_exp_f32 %0, %1" : "=v"(r) : "v"(x));
    return r;
}

#define TILE_B 16384
#define WS_VT  33554432u
#define WS_NEED 67108864u

typedef const uint32_t __attribute__((address_space(1))) ga_u32;
typedef uint32_t __attribute__((address_space(3))) la_u32;
__device__ __forceinline__ void gload16(void* l, const void* g) {
    __builtin_amdgcn_global_load_lds((ga_u32*)g, (la_u32*)l, 16, 0, 0);
}

// ---- phase 0: K -> f16 swizzled (16-deep) 64x128 tiles;
//      V -> V^T f16, d-pair-interleaved 256B rows, 16-deep swizzle ----
__global__ __launch_bounds__(256, 4)
void conv_kv(const float* __restrict__ K, const float* __restrict__ V,
             char* __restrict__ kf, char* __restrict__ vt)
{
    size_t tile = blockIdx.x;                       // bh*32 + s/64
    const float4* kg = (const float4*)(K + tile * (64 * 128));
    char* kd = kf + tile * TILE_B;
    #pragma unroll
    for (int it = 0; it < 8; ++it) {
        int idx = it * 256 + threadIdx.x;           // float4 index in tile
        int row = idx >> 5;
        int d0  = (idx & 31) * 4;
        float4 kk = kg[idx];
        uint32_t a = pkf16(kk.x, kk.y);
        uint32_t b = pkf16(kk.z, kk.w);
        uint32_t byte = (uint32_t)((row * 256 + d0 * 2) ^ ((row & 15) << 4));
        *(uint32_t*)(kd + byte)     = a;
        *(uint32_t*)(kd + byte + 4) = b;
    }
    const float* vs = V + tile * (64 * 128);
    char* vd = vt + tile * TILE_B;
    #pragma unroll
    for (int it = 0; it < 8; ++it) {
        int idx = it * 256 + threadIdx.x;
        int d  = idx & 127;
        int k0 = (idx >> 7) * 4;                    // 0,4,...,60
        uint32_t a = pkf16(vs[(k0 + 0) * 128 + d], vs[(k0 + 1) * 128 + d]);
        uint32_t b = pkf16(vs[(k0 + 2) * 128 + d], vs[(k0 + 3) * 128 + d]);
        uint32_t byte = (uint32_t)(((d >> 1) * 256 + (k0 >> 3) * 32 + (d & 1) * 16 + (k0 & 7) * 2)
                                   ^ (((d >> 1) & 15) << 4));
        *(uint32_t*)(vd + byte)     = a;
        *(uint32_t*)(vd + byte + 4) = b;
    }
}

// ---- main: flash attention f16, 32x32x16 MFMA, 8 waves x 32 q-rows,
//      carried-S pipeline + wave-group phase offset:
//      even waves {QK^T[t]; FINISH[t-1]}, odd waves {FINISH[t-1]; QK^T[t]} ----
__global__ __launch_bounds__(512, 2)
void attn32(const float* __restrict__ Q, const char* __restrict__ ws,
            float* __restrict__ O)
{
    __shared__ __align__(16) char lds[131072];  // 4 x [K 16K | V^T 16K]

    const int tid  = threadIdx.x;
    const int w    = tid >> 6;      // 0..7
    const int lane = tid & 63;
    const int ql   = lane & 31;     // q column in sacc; also k-row / d-row for frags
    const int h    = lane >> 5;     // half

    // chunked XCD swizzle: each XCD gets 64 consecutive new-ids = 8 heads
    const int fid  = blockIdx.x;               // 0..511
    const int nid  = (fid & 7) * 64 + (fid >> 3);
    const int qblk = nid & 7;
    const int bh   = nid >> 3;

    const size_t base = (size_t)bh * S_LEN * D_DIM;
    const int qrow0 = qblk * 256 + w * 32;

    // Q f16 fragments scaled by log2(e) (B-operand: n=q=ql, k=16c+8h+j)
    const float L2E = 1.44269504f;
    f16x8 qf[8];
    {
        const float* qp = Q + base + (size_t)(qrow0 + ql) * D_DIM;
        #pragma unroll
        for (int c = 0; c < 8; ++c) {
            const int d0 = c * 16 + h * 8;
            float4 f0 = *(const float4*)(qp + d0);
            float4 f1 = *(const float4*)(qp + d0 + 4);
            qf[c][0] = (f16_t)(f0.x * L2E); qf[c][1] = (f16_t)(f0.y * L2E);
            qf[c][2] = (f16_t)(f0.z * L2E); qf[c][3] = (f16_t)(f0.w * L2E);
            qf[c][4] = (f16_t)(f1.x * L2E); qf[c][5] = (f16_t)(f1.y * L2E);
            qf[c][6] = (f16_t)(f1.z * L2E); qf[c][7] = (f16_t)(f1.w * L2E);
        }
    }
    // clean vmcnt slate before manual counting starts
    asm volatile("s_waitcnt vmcnt(0)" ::: "memory");

    f32x16 oacc[4];
    #pragma unroll
    for (int nt = 0; nt < 4; ++nt)
        #pragma unroll
        for (int r = 0; r < 16; ++r) oacc[nt][r] = 0.f;
    float m_run = -INFINITY, l_run = 0.f;   // base-2 units

    const char* kf_t = ws + (size_t)(bh * 32) * TILE_B;
    const char* vt_t = ws + WS_VT + (size_t)(bh * 32) * TILE_B;
    const int swk = (ql & 15) << 4;          // K-tile read swizzle (16-deep)
    const int vbase = (ql >> 1) * 256 + (ql & 1) * 16;   // V-tile per-lane base
    const int swv = (ql >> 1) << 4;          // V-tile read swizzle

    // prologue: stage tiles 0,1,2 into bufs 0,1,2
    #pragma unroll
    for (int tt = 0; tt < 3; ++tt) {
        #pragma unroll
        for (int j = 0; j < 2; ++j) {
            const int off = j * 8192 + w * 1024;
            gload16(lds + tt * 32768 + off,         kf_t + off + lane * 16);
            gload16(lds + tt * 32768 + 16384 + off, vt_t + off + lane * 16);
        }
        kf_t += TILE_B; vt_t += TILE_B;
    }
    asm volatile("s_waitcnt vmcnt(8)" ::: "memory");   // tile 0 landed
    asm volatile("s_barrier" ::: "memory");

    // pipeline head: S^T[0] into carried registers
    f32x16 s0p, s1p;
    {
        #pragma unroll
        for (int r = 0; r < 16; ++r) { s0p[r] = 0.f; s1p[r] = 0.f; }
        __builtin_amdgcn_s_setprio(1);
        #pragma unroll
        for (int c = 0; c < 8; ++c) {
            const int b0 = (ql * 256 + c * 32 + h * 16) ^ swk;
            f16x8 a0 = *(const f16x8*)(lds + b0);
            f16x8 a1 = *(const f16x8*)(lds + b0 + 8192);
            s0p = __builtin_amdgcn_mfma_f32_32x32x16_f16(a0, qf[c], s0p, 0, 0, 0);
            s1p = __builtin_amdgcn_mfma_f32_32x32x16_f16(a1, qf[c], s1p, 0, 0, 0);
        }
        __builtin_amdgcn_s_setprio(0);
    }

    int rdb = 32768;   // K buf for tile t
    int rdp = 0;       // V buf for tile t-1
    int stb = 98304;   // stage buf for tile t+2
    for (int t6 = 1; t6 < 32; ++t6) {
        // own tile-t loads done (next tile's 4 may stay in flight); then barrier
        if (t6 == 31) { asm volatile("s_waitcnt vmcnt(0)" ::: "memory"); }
        else          { asm volatile("s_waitcnt vmcnt(4)" ::: "memory"); }
        asm volatile("s_barrier" ::: "memory");

        // issue tile t+2 stage (its buffer's last read was separated by this barrier)
        if (t6 <= 29) {
            #pragma unroll
            for (int j = 0; j < 2; ++j) {
                const int off = j * 8192 + w * 1024;
                gload16(lds + stb + off,         kf_t + off + lane * 16);
                gload16(lds + stb + 16384 + off, vt_t + off + lane * 16);
            }
            kf_t += TILE_B; vt_t += TILE_B;
            stb = (stb == 98304) ? 0 : stb + 32768;
        }

        f32x16 s0, s1;   // S^T[t], computed by QKT block below

        // ---- macro-block A: S^T[t] = K Q^T (LDS + MFMA heavy) ----
        auto QKT = [&]() {
            #pragma unroll
            for (int r = 0; r < 16; ++r) { s0[r] = 0.f; s1[r] = 0.f; }
            __builtin_amdgcn_s_setprio(1);
            #pragma unroll
            for (int c = 0; c < 8; ++c) {
                const int b0 = (ql * 256 + c * 32 + h * 16) ^ swk;
                f16x8 a0 = *(const f16x8*)(lds + rdb + b0);
                f16x8 a1 = *(const f16x8*)(lds + rdb + b0 + 8192);
                s0 = __builtin_amdgcn_mfma_f32_32x32x16_f16(a0, qf[c], s0, 0, 0, 0);
                s1 = __builtin_amdgcn_mfma_f32_32x32x16_f16(a1, qf[c], s1, 0, 0, 0);
            }
            __builtin_amdgcn_s_setprio(0);
        };

        // ---- macro-block B: softmax+pack+PV of tile t-1 (VALU heavy, then MFMA) ----
        auto FINISH = [&]() {
            float tm = fmaxf(s0p[0], s1p[0]);
            #pragma unroll
            for (int r = 1; r < 16; ++r)
                tm = fmaxf(tm, fmaxf(s0p[r], s1p[r]));
            {
                uint32x2 ts = plswap(__float_as_uint(tm), __float_as_uint(tm));
                tm = fmaxf(__uint_as_float(ts[0]), __uint_as_float(ts[1]));
            }
            if (__any(tm > m_run + 11.f)) {
                const float mn = fmaxf(m_run, tm);
                const float sc = exp2_fast(m_run - mn);
                m_run = mn;
                l_run *= sc;
                #pragma unroll
                for (int r = 0; r < 16; ++r) {
                    const float scq = __shfl(sc, (r & 3) + 8 * (r >> 2) + 4 * h);
                    oacc[0][r] *= scq; oacc[1][r] *= scq;
                    oacc[2][r] *= scq; oacc[3][r] *= scq;
                }
            }
            float ps = 0.f;
            #pragma unroll
            for (int r = 0; r < 16; ++r) {
                float p0 = exp2_fast(s0p[r] - m_run); s0p[r] = p0; ps += p0;
                float p1 = exp2_fast(s1p[r] - m_run); s1p[r] = p1; ps += p1;
            }
            {
                uint32x2 pss = plswap(__float_as_uint(ps), __float_as_uint(ps));
                ps = __uint_as_float(pss[0]) + __uint_as_float(pss[1]);
            }
            l_run += ps;

            f16x8 pf[4];
            {
                uint32_t pk[8];
                #pragma unroll
                for (int i = 0; i < 8; ++i) pk[i] = pkf16(s0p[2 * i], s0p[2 * i + 1]);
                uint32x2 r02 = plswap(pk[0], pk[2]), r13 = plswap(pk[1], pk[3]);
                uint32x2 r46 = plswap(pk[4], pk[6]), r57 = plswap(pk[5], pk[7]);
                union { uint32_t u[4]; f16x8 v; } b0, b1;
                b0.u[0] = r02[0]; b0.u[1] = r13[0]; b0.u[2] = r02[1]; b0.u[3] = r13[1];
                b1.u[0] = r46[0]; b1.u[1] = r57[0]; b1.u[2] = r46[1]; b1.u[3] = r57[1];
                pf[0] = b0.v; pf[1] = b1.v;
            }
            {
                uint32_t pk[8];
                #pragma unroll
                for (int i = 0; i < 8; ++i) pk[i] = pkf16(s1p[2 * i], s1p[2 * i + 1]);
                uint32x2 r02 = plswap(pk[0], pk[2]), r13 = plswap(pk[1], pk[3]);
                uint32x2 r46 = plswap(pk[4], pk[6]), r57 = plswap(pk[5], pk[7]);
                union { uint32_t u[4]; f16x8 v; } b0, b1;
                b0.u[0] = r02[0]; b0.u[1] = r13[0]; b0.u[2] = r02[1]; b0.u[3] = r13[1];
                b1.u[0] = r46[0]; b1.u[1] = r57[0]; b1.u[2] = r46[1]; b1.u[3] = r57[1];
                pf[2] = b0.v; pf[3] = b1.v;
            }

            __builtin_amdgcn_s_setprio(1);
            #pragma unroll
            for (int nt = 0; nt < 4; ++nt) {
                #pragma unroll
                for (int kc = 0; kc < 4; ++kc) {
                    const int byte = (nt * 4096 + vbase + (kc * 2 + h) * 32) ^ swv;
                    f16x8 vb = *(const f16x8*)(lds + rdp + 16384 + byte);
                    oacc[nt] = __builtin_amdgcn_mfma_f32_32x32x16_f16(pf[kc], vb, oacc[nt], 0, 0, 0);
                }
            }
            __builtin_amdgcn_s_setprio(0);
        };

        // wave-group phase offset: even waves LDS/MFMA-first, odd waves VALU-first
        if ((w & 1) == 0) { QKT(); FINISH(); }
        else              { FINISH(); QKT(); }

        // ---- shift pipeline: S[t] becomes S[t-1] ----
        #pragma unroll
        for (int r = 0; r < 16; ++r) { s0p[r] = s0[r]; s1p[r] = s1[r]; }
        rdp = rdb;
        rdb = (rdb == 98304) ? 0 : rdb + 32768;
    }

    // ---- pipeline tail: softmax+pack+PV of tile 31 (V in buf rdp) ----
    {
        float tm = fmaxf(s0p[0], s1p[0]);
        #pragma unroll
        for (int r = 1; r < 16; ++r)
            tm = fmaxf(tm, fmaxf(s0p[r], s1p[r]));
        {
            uint32x2 ts = plswap(__float_as_uint(tm), __float_as_uint(tm));
            tm = fmaxf(__uint_as_float(ts[0]), __uint_as_float(ts[1]));
        }
        if (__any(tm > m_run + 11.f)) {
            const float mn = fmaxf(m_run, tm);
            const float sc = exp2_fast(m_run - mn);
            m_run = mn;
            l_run *= sc;
            #pragma unroll
            for (int r = 0; r < 16; ++r) {
                const float scq = __shfl(sc, (r & 3) + 8 * (r >> 2) + 4 * h);
                oacc[0][r] *= scq; oacc[1][r] *= scq;
                oacc[2][r] *= scq; oacc[3][r] *= scq;
            }
        }
        float ps = 0.f;
        #pragma unroll
        for (int r = 0; r < 16; ++r) {
            float p0 = exp2_fast(s0p[r] - m_run); s0p[r] = p0; ps += p0;
            float p1 = exp2_fast(s1p[r] - m_run); s1p[r] = p1; ps += p1;
        }
        {
            uint32x2 pss = plswap(__float_as_uint(ps), __float_as_uint(ps));
            ps = __uint_as_float(pss[0]) + __uint_as_float(pss[1]);
        }
        l_run += ps;

        f16x8 pf[4];
        {
            uint32_t pk[8];
            #pragma unroll
            for (int i = 0; i < 8; ++i) pk[i] = pkf16(s0p[2 * i], s0p[2 * i + 1]);
            uint32x2 r02 = plswap(pk[0], pk[2]), r13 = plswap(pk[1], pk[3]);
            uint32x2 r46 = plswap(pk[4], pk[6]), r57 = plswap(pk[5], pk[7]);
            union { uint32_t u[4]; f16x8 v; } b0, b1;
            b0.u[0] = r02[0]; b0.u[1] = r13[0]; b0.u[2] = r02[1]; b0.u[3] = r13[1];
            b1.u[0] = r46[0]; b1.u[1] = r57[0]; b1.u[2] = r46[1]; b1.u[3] = r57[1];
            pf[0] = b0.v; pf[1] = b1.v;
        }
        {
            uint32_t pk[8];
            #pragma unroll
            for (int i = 0; i < 8; ++i) pk[i] = pkf16(s1p[2 * i], s1p[2 * i + 1]);
            uint32x2 r02 = plswap(pk[0], pk[2]), r13 = plswap(pk[1], pk[3]);
            uint32x2 r46 = plswap(pk[4], pk[6]), r57 = plswap(pk[5], pk[7]);
            union { uint32_t u[4]; f16x8 v; } b0, b1;
            b0.u[0] = r02[0]; b0.u[1] = r13[0]; b0.u[2] = r02[1]; b0.u[3] = r13[1];
            b1.u[0] = r46[0]; b1.u[1] = r57[0]; b1.u[2] = r46[1]; b1.u[3] = r57[1];
            pf[2] = b0.v; pf[3] = b1.v;
        }

        __builtin_amdgcn_s_setprio(1);
        #pragma unroll
        for (int nt = 0; nt < 4; ++nt) {
            #pragma unroll
            for (int kc = 0; kc < 4; ++kc) {
                const int byte = (nt * 4096 + vbase + (kc * 2 + h) * 32) ^ swv;
                f16x8 vb = *(const f16x8*)(lds + rdp + 16384 + byte);
                oacc[nt] = __builtin_amdgcn_mfma_f32_32x32x16_f16(pf[kc], vb, oacc[nt], 0, 0, 0);
            }
        }
        __builtin_amdgcn_s_setprio(0);
    }

    // ---- epilogue: O[qrow0+qr][nt*32+ql], qr = (r&3)+8*(r>>2)+4h ----
    const float inv = 1.f / l_run;
    #pragma unroll
    for (int r = 0; r < 16; ++r) {
        const int qr = (r & 3) + 8 * (r >> 2) + 4 * h;
        const float iv = __shfl(inv, qr);
        float* op = O + base + (size_t)(qrow0 + qr) * D_DIM + ql;
        op[0]  = oacc[0][r] * iv;
        op[32] = oacc[1][r] * iv;
        op[64] = oacc[2][r] * iv;
        op[96] = oacc[3][r] * iv;
    }
}

// ================= fallback (round-1 kernel, passes without ws) =================
#define PADK 136
#define PADV 72
#define LDS_SHORTS 31232

__global__ __launch_bounds__(256, 2)
void attn_fwd_fb(const float* __restrict__ Q, const float* __restrict__ K,
                 const float* __restrict__ V, float* __restrict__ O)
{
    __shared__ short lds[LDS_SHORTS];
    short* khi = lds;
    short* klo = lds + 8704;
    short* vt  = lds + 17408;
    short* pls = lds + 26624;

    const int tid  = threadIdx.x;
    const int w    = tid >> 6;
    const int lane = tid & 63;
    const int lg   = lane & 15;
    const int gq   = lane >> 4;
    const int qblk = blockIdx.x;
    const int bh   = blockIdx.y;
    const size_t base = (size_t)bh * S_LEN * D_DIM;
    const int qrow0 = qblk * 64 + w * 16;

    bf8_t qhi[4], qlo[4];
    {
        const float* qp = Q + base + (size_t)(qrow0 + lg) * D_DIM;
        #pragma unroll
        for (int c = 0; c < 4; ++c) {
            const int d0 = c * 32 + gq * 8;
            #pragma unroll
            for (int j = 0; j < 8; ++j) {
                float f = qp[d0 + j];
                short hh = f2bf(f);
                qhi[c][j] = hh;
                qlo[c][j] = f2bf(f - bf2f(hh));
            }
        }
    }

    f32x4 oacc[8];
    #pragma unroll
    for (int n = 0; n < 8; ++n) oacc[n] = (f32x4){0.f, 0.f, 0.f, 0.f};
    float mrow[4] = {-INFINITY, -INFINITY, -INFINITY, -INFINITY};
    float lrow[4] = {0.f, 0.f, 0.f, 0.f};

    for (int kv = 0; kv < S_LEN; kv += 64) {
        __syncthreads();
        {
            const float4* kg = (const float4*)(K + base + (size_t)kv * D_DIM);
            const float4* vg = (const float4*)(V + base + (size_t)kv * D_DIM);
            #pragma unroll
            for (int it = 0; it < 8; ++it) {
                const int f4  = it * 256 + tid;
                const int row = f4 >> 5;
                const int d   = (f4 & 31) * 4;
                float4 kk = kg[f4];
                float4 vv = vg[f4];
                short h0 = f2bf(kk.x), h1 = f2bf(kk.y), h2 = f2bf(kk.z), h3 = f2bf(kk.w);
                short4 hw; hw.x = h0; hw.y = h1; hw.z = h2; hw.w = h3;
                *(short4*)(&khi[row * PADK + d]) = hw;
                short4 lw;
                lw.x = f2bf(kk.x - bf2f(h0));
                lw.y = f2bf(kk.y - bf2f(h1));
                lw.z = f2bf(kk.z - bf2f(h2));
                lw.w = f2bf(kk.w - bf2f(h3));
                *(short4*)(&klo[row * PADK + d]) = lw;
                vt[(d + 0) * PADV + row] = f2bf(vv.x);
                vt[(d + 1) * PADV + row] = f2bf(vv.y);
                vt[(d + 2) * PADV + row] = f2bf(vv.z);
                vt[(d + 3) * PADV + row] = f2bf(vv.w);
            }
        }
        __syncthreads();

        f32x4 sacc[4];
        #pragma unroll
        for (int t = 0; t < 4; ++t) sacc[t] = (f32x4){0.f, 0.f, 0.f, 0.f};
        #pragma unroll
        for (int t = 0; t < 4; ++t) {
            const int krow = t * 16 + lg;
            #pragma unroll
            for (int c = 0; c < 4; ++c) {
                bf8_t kh = *(const bf8_t*)(&khi[krow * PADK + c * 32 + gq * 8]);
                bf8_t kl = *(const bf8_t*)(&klo[krow * PADK + c * 32 + gq * 8]);
                sacc[t] = __builtin_amdgcn_mfma_f32_16x16x32_bf16(qhi[c], kh, sacc[t], 0, 0, 0);
                sacc[t] = __builtin_amdgcn_mfma_f32_16x16x32_bf16(qlo[c], kh, sacc[t], 0, 0, 0);
                sacc[t] = __builtin_amdgcn_mfma_f32_16x16x32_bf16(qhi[c], kl, sacc[t], 0, 0, 0);
            }
        }

        float scl[4];
        #pragma unroll
        for (int r = 0; r < 4; ++r) {
            float tm = fmaxf(fmaxf(sacc[0][r], sacc[1][r]),
                             fmaxf(sacc[2][r], sacc[3][r]));
            #pragma unroll
            for (int off = 8; off >= 1; off >>= 1)
                tm = fmaxf(tm, __shfl_xor(tm, off, 64));
            const float mn = fmaxf(mrow[r], tm);
            const float sc = __expf(mrow[r] - mn);
            float ps = 0.f;
            #pragma unroll
            for (int t = 0; t < 4; ++t) {
                float p = __expf(sacc[t][r] - mn);
                sacc[t][r] = p;
                ps += p;
            }
            #pragma unroll
            for (int off = 8; off >= 1; off >>= 1)
                ps += __shfl_xor(ps, off, 64);
            lrow[r] = lrow[r] * sc + ps;
            mrow[r] = mn;
            scl[r] = sc;
        }
        #pragma unroll
        for (int n = 0; n < 8; ++n) {
            oacc[n][0] *= scl[0];
            oacc[n][1] *= scl[1];
            oacc[n][2] *= scl[2];
            oacc[n][3] *= scl[3];
        }

        short* pw = pls + w * (16 * PADV);
        #pragma unroll
        for (int t = 0; t < 4; ++t)
            #pragma unroll
            for (int r = 0; r < 4; ++r)
                pw[(gq * 4 + r) * PADV + t * 16 + lg] = f2bf(sacc[t][r]);
        asm volatile("s_waitcnt lgkmcnt(0)" ::: "memory");

        #pragma unroll
        for (int kt = 0; kt < 2; ++kt) {
            bf8_t pa = *(const bf8_t*)(&pw[lg * PADV + kt * 32 + gq * 8]);
            #pragma unroll
            for (int n = 0; n < 8; ++n) {
                bf8_t vb = *(const bf8_t*)(&vt[(n * 16 + lg) * PADV + kt * 32 + gq * 8]);
                oacc[n] = __builtin_amdgcn_mfma_f32_16x16x32_bf16(pa, vb, oacc[n], 0, 0, 0);
            }
        }
    }

    float inv[4];
    #pragma unroll
    for (int r = 0; r < 4; ++r) inv[r] = 1.f / lrow[r];
    float* op = O + base + (size_t)qrow0 * D_DIM;
    #pragma unroll
    for (int n = 0; n < 8; ++n)
        #pragma unroll
        for (int r = 0; r < 4; ++r)
            op[(size_t)(gq * 4 + r) * D_DIM + n * 16 + lg] = oacc[n][r] * inv[r];
}

extern "C" void kernel_launch(void* const* d_in, const int* in_sizes, int n_in,
                              void* d_out, int out_size, void* d_ws, size_t ws_size,
                              hipStream_t stream) {
    const float* q = (const float*)d_in[0];
    const float* k = (const float*)d_in[1];
    const float* v = (const float*)d_in[2];
    float* o = (float*)d_out;
    if (ws_size >= (size_t)WS_NEED) {
        char* ws = (char*)d_ws;
        conv_kv<<<2048, 256, 0, stream>>>(k, v, ws, ws + WS_VT);
        attn32<<<512, 512, 0, stream>>>(q, ws, o);
    } else {
        attn_fwd_fb<<<dim3(32, 64), 256, 0, stream>>>(q, k, v, o);
    }
}

// Round 16
// 211.905 us; speedup vs baseline: 1.0434x; 1.0434x over previous
//
#include <hip/hip_runtime.h>
#include <hip/hip_bf16.h>
#include <math.h>
#include <stdint.h>

#define S_LEN 2048
#define D_DIM 128

typedef _Float16 f16x8 __attribute__((ext_vector_type(8)));
typedef __fp16  fp16x2 __attribute__((ext_vector_type(2)));   // cvt_pkrtz return type
typedef short bf8_t __attribute__((ext_vector_type(8)));
typedef float f32x4 __attribute__((ext_vector_type(4)));
typedef float f32x16 __attribute__((ext_vector_type(16)));
typedef unsigned int uint32x2 __attribute__((ext_vector_type(2)));
typedef _Float16 f16_t;

__device__ __forceinline__ short f2bf(float f) {
    union { float f; unsigned u; } x; x.f = f;
    unsigned u = x.u;
    u += 0x7FFF + ((u >> 16) & 1);
    return (short)(u >> 16);
}
__device__ __forceinline__ float bf2f(short h) {
    union { unsigned u; float f; } x;
    x.u = ((unsigned)(unsigned short)h) << 16;
    return x.f;
}
__device__ __forceinline__ uint32_t pkf16(float a, float b) {
    union { fp16x2 h; uint32_t u; } x;
    x.h = __builtin_amdgcn_cvt_pkrtz(a, b);
    return x.u;
}
__device__ __forceinline__ uint32x2 plswap(uint32_t a, uint32_t b) {
    return __builtin_amdgcn_permlane32_swap(a, b, false, false);
}
// bare v_exp_f32: computes 2^x in one instruction
__device__ __forceinline__ float exp2_fast(float x) {
    float r;
    asm("v_exp_f32 %0, %1" : "=v"(r) : "v"(x));
    return r;
}

#define TILE_B 16384
#define WS_VT  33554432u
#define WS_NEED 67108864u

typedef const uint32_t __attribute__((address_space(1))) ga_u32;
typedef uint32_t __attribute__((address_space(3))) la_u32;
__device__ __forceinline__ void gload16(void* l, const void* g) {
    __builtin_amdgcn_global_load_lds((ga_u32*)g, (la_u32*)l, 16, 0, 0);
}

// ---- phase 0: K -> f16 swizzled (16-deep) 64x128 tiles;
//      V -> V^T f16, d-pair-interleaved 256B rows, 16-deep swizzle ----
__global__ __launch_bounds__(256, 4)
void conv_kv(const float* __restrict__ K, const float* __restrict__ V,
             char* __restrict__ kf, char* __restrict__ vt)
{
    size_t tile = blockIdx.x;                       // bh*32 + s/64
    const float4* kg = (const float4*)(K + tile * (64 * 128));
    char* kd = kf + tile * TILE_B;
    #pragma unroll
    for (int it = 0; it < 8; ++it) {
        int idx = it * 256 + threadIdx.x;           // float4 index in tile
        int row = idx >> 5;
        int d0  = (idx & 31) * 4;
        float4 kk = kg[idx];
        uint32_t a = pkf16(kk.x, kk.y);
        uint32_t b = pkf16(kk.z, kk.w);
        uint32_t byte = (uint32_t)((row * 256 + d0 * 2) ^ ((row & 15) << 4));
        *(uint32_t*)(kd + byte)     = a;
        *(uint32_t*)(kd + byte + 4) = b;
    }
    const float* vs = V + tile * (64 * 128);
    char* vd = vt + tile * TILE_B;
    #pragma unroll
    for (int it = 0; it < 8; ++it) {
        int idx = it * 256 + threadIdx.x;
        int d  = idx & 127;
        int k0 = (idx >> 7) * 4;                    // 0,4,...,60
        uint32_t a = pkf16(vs[(k0 + 0) * 128 + d], vs[(k0 + 1) * 128 + d]);
        uint32_t b = pkf16(vs[(k0 + 2) * 128 + d], vs[(k0 + 3) * 128 + d]);
        uint32_t byte = (uint32_t)(((d >> 1) * 256 + (k0 >> 3) * 32 + (d & 1) * 16 + (k0 & 7) * 2)
                                   ^ (((d >> 1) & 15) << 4));
        *(uint32_t*)(vd + byte)     = a;
        *(uint32_t*)(vd + byte + 4) = b;
    }
}

// ---- main: flash attention f16, 32x32x16 MFMA, 8 waves x 32 q-rows,
//      3-buffer 2-deep prefetch, counted vmcnt, conflict-free swizzles ----
__global__ __launch_bounds__(512, 2)
void attn32(const float* __restrict__ Q, const char* __restrict__ ws,
            float* __restrict__ O)
{
    __shared__ __align__(16) char lds[98304];  // 3 x [K 16K | V^T 16K]

    const int tid  = threadIdx.x;
    const int w    = tid >> 6;      // 0..7
    const int lane = tid & 63;
    const int ql   = lane & 31;     // q column in sacc; also k-row / d-row for frags
    const int h    = lane >> 5;     // half

    // chunked XCD swizzle: each XCD gets 64 consecutive new-ids = 8 heads
    const int fid  = blockIdx.x;               // 0..511
    const int nid  = (fid & 7) * 64 + (fid >> 3);
    const int qblk = nid & 7;
    const int bh   = nid >> 3;

    const size_t base = (size_t)bh * S_LEN * D_DIM;
    const int qrow0 = qblk * 256 + w * 32;

    // Q f16 fragments scaled by log2(e) (B-operand: n=q=ql, k=16c+8h+j)
    const float L2E = 1.44269504f;
    f16x8 qf[8];
    {
        const float* qp = Q + base + (size_t)(qrow0 + ql) * D_DIM;
        #pragma unroll
        for (int c = 0; c < 8; ++c) {
            const int d0 = c * 16 + h * 8;
            float4 f0 = *(const float4*)(qp + d0);
            float4 f1 = *(const float4*)(qp + d0 + 4);
            qf[c][0] = (f16_t)(f0.x * L2E); qf[c][1] = (f16_t)(f0.y * L2E);
            qf[c][2] = (f16_t)(f0.z * L2E); qf[c][3] = (f16_t)(f0.w * L2E);
            qf[c][4] = (f16_t)(f1.x * L2E); qf[c][5] = (f16_t)(f1.y * L2E);
            qf[c][6] = (f16_t)(f1.z * L2E); qf[c][7] = (f16_t)(f1.w * L2E);
        }
    }
    // clean vmcnt slate before manual counting starts
    asm volatile("s_waitcnt vmcnt(0)" ::: "memory");

    f32x16 oacc[4];
    #pragma unroll
    for (int nt = 0; nt < 4; ++nt)
        #pragma unroll
        for (int r = 0; r < 16; ++r) oacc[nt][r] = 0.f;
    float m_run = -INFINITY, l_run = 0.f;   // base-2 units

    const char* kf_t = ws + (size_t)(bh * 32) * TILE_B;
    const char* vt_t = ws + WS_VT + (size_t)(bh * 32) * TILE_B;
    const int swk = (ql & 15) << 4;          // K-tile read swizzle (16-deep)
    const int vbase = (ql >> 1) * 256 + (ql & 1) * 16;   // V-tile per-lane base
    const int swv = (ql >> 1) << 4;          // V-tile read swizzle

    // prologue: stage tiles 0,1 into bufs 0,1 (4 loads/wave each)
    #pragma unroll
    for (int tt = 0; tt < 2; ++tt) {
        #pragma unroll
        for (int j = 0; j < 2; ++j) {
            const int off = j * 8192 + w * 1024;
            gload16(lds + tt * 32768 + off,         kf_t + off + lane * 16);
            gload16(lds + tt * 32768 + 16384 + off, vt_t + off + lane * 16);
        }
        kf_t += TILE_B; vt_t += TILE_B;
    }

    int rdb = 0;       // read-buffer byte offset (tile t)
    int stb = 65536;   // stage-buffer byte offset (tile t+2)
    for (int t6 = 0; t6 < 32; ++t6) {
        // own tile-t loads done (t+1's 4 may stay in flight); then all-waves barrier
        if (t6 == 31) { asm volatile("s_waitcnt vmcnt(0)" ::: "memory"); }
        else          { asm volatile("s_waitcnt vmcnt(4)" ::: "memory"); }
        asm volatile("s_barrier" ::: "memory");

        // issue tile t+2 stage (buffer freed by iter t-1, safe past barrier)
        if (t6 < 30) {
            #pragma unroll
            for (int j = 0; j < 2; ++j) {
                const int off = j * 8192 + w * 1024;
                gload16(lds + stb + off,         kf_t + off + lane * 16);
                gload16(lds + stb + 16384 + off, vt_t + off + lane * 16);
            }
            kf_t += TILE_B; vt_t += TILE_B;
            stb = (stb == 65536) ? 0 : stb + 32768;
        }

        // ---- S^T = K Q^T (two 32x32 tiles over k), base-2 logits ----
        f32x16 s0, s1;
        #pragma unroll
        for (int r = 0; r < 16; ++r) { s0[r] = 0.f; s1[r] = 0.f; }
        __builtin_amdgcn_s_setprio(1);
        #pragma unroll
        for (int c = 0; c < 8; ++c) {
            const int b0 = (ql * 256 + c * 32 + h * 16) ^ swk;
            f16x8 a0 = *(const f16x8*)(lds + rdb + b0);
            f16x8 a1 = *(const f16x8*)(lds + rdb + b0 + 8192);
            s0 = __builtin_amdgcn_mfma_f32_32x32x16_f16(a0, qf[c], s0, 0, 0, 0);
            s1 = __builtin_amdgcn_mfma_f32_32x32x16_f16(a1, qf[c], s1, 0, 0, 0);
        }
        __builtin_amdgcn_s_setprio(0);

        // ---- online softmax: row q=ql lives in lanes {l, l^32} only ----
        float tm = fmaxf(s0[0], s1[0]);
        #pragma unroll
        for (int r = 1; r < 16; ++r)
            tm = fmaxf(tm, fmaxf(s0[r], s1[r]));   // -> v_max3 chain
        {
            uint32x2 ts = plswap(__float_as_uint(tm), __float_as_uint(tm));
            tm = fmaxf(__uint_as_float(ts[0]), __uint_as_float(ts[1]));
        }
        if (__any(tm > m_run + 11.f)) {
            const float mn = fmaxf(m_run, tm);
            const float sc = exp2_fast(m_run - mn);
            m_run = mn;
            l_run *= sc;
            #pragma unroll
            for (int r = 0; r < 16; ++r) {
                const float scq = __shfl(sc, (r & 3) + 8 * (r >> 2) + 4 * h);
                oacc[0][r] *= scq; oacc[1][r] *= scq;
                oacc[2][r] *= scq; oacc[3][r] *= scq;
            }
        }
        float ps = 0.f;
        #pragma unroll
        for (int r = 0; r < 16; ++r) {
            float p0 = exp2_fast(s0[r] - m_run); s0[r] = p0; ps += p0;
            float p1 = exp2_fast(s1[r] - m_run); s1[r] = p1; ps += p1;
        }
        {
            uint32x2 pss = plswap(__float_as_uint(ps), __float_as_uint(ps));
            ps = __uint_as_float(pss[0]) + __uint_as_float(pss[1]);
        }
        l_run += ps;

        // ---- pack P to f16, build A-frags via permlane32_swap (no LDS) ----
        f16x8 pf[4];
        {
            uint32_t pk[8];
            #pragma unroll
            for (int i = 0; i < 8; ++i) pk[i] = pkf16(s0[2 * i], s0[2 * i + 1]);
            uint32x2 r02 = plswap(pk[0], pk[2]), r13 = plswap(pk[1], pk[3]);
            uint32x2 r46 = plswap(pk[4], pk[6]), r57 = plswap(pk[5], pk[7]);
            union { uint32_t u[4]; f16x8 v; } b0, b1;
            b0.u[0] = r02[0]; b0.u[1] = r13[0]; b0.u[2] = r02[1]; b0.u[3] = r13[1];
            b1.u[0] = r46[0]; b1.u[1] = r57[0]; b1.u[2] = r46[1]; b1.u[3] = r57[1];
            pf[0] = b0.v; pf[1] = b1.v;
        }
        {
            uint32_t pk[8];
            #pragma unroll
            for (int i = 0; i < 8; ++i) pk[i] = pkf16(s1[2 * i], s1[2 * i + 1]);
            uint32x2 r02 = plswap(pk[0], pk[2]), r13 = plswap(pk[1], pk[3]);
            uint32x2 r46 = plswap(pk[4], pk[6]), r57 = plswap(pk[5], pk[7]);
            union { uint32_t u[4]; f16x8 v; } b0, b1;
            b0.u[0] = r02[0]; b0.u[1] = r13[0]; b0.u[2] = r02[1]; b0.u[3] = r13[1];
            b1.u[0] = r46[0]; b1.u[1] = r57[0]; b1.u[2] = r46[1]; b1.u[3] = r57[1];
            pf[2] = b0.v; pf[3] = b1.v;
        }

        // ---- O += P V  (A=P frags, B=V^T d-pair-interleaved from LDS) ----
        __builtin_amdgcn_s_setprio(1);
        #pragma unroll
        for (int nt = 0; nt < 4; ++nt) {
            #pragma unroll
            for (int kc = 0; kc < 4; ++kc) {
                const int byte = (nt * 4096 + vbase + (kc * 2 + h) * 32) ^ swv;
                f16x8 vb = *(const f16x8*)(lds + rdb + 16384 + byte);
                oacc[nt] = __builtin_amdgcn_mfma_f32_32x32x16_f16(pf[kc], vb, oacc[nt], 0, 0, 0);
            }
        }
        __builtin_amdgcn_s_setprio(0);

        rdb = (rdb == 65536) ? 0 : rdb + 32768;
    }

    // ---- epilogue: O[qrow0+qr][nt*32+ql], qr = (r&3)+8*(r>>2)+4h ----
    const float inv = 1.f / l_run;
    #pragma unroll
    for (int r = 0; r < 16; ++r) {
        const int qr = (r & 3) + 8 * (r >> 2) + 4 * h;
        const float iv = __shfl(inv, qr);
        float* op = O + base + (size_t)(qrow0 + qr) * D_DIM + ql;
        op[0]  = oacc[0][r] * iv;
        op[32] = oacc[1][r] * iv;
        op[64] = oacc[2][r] * iv;
        op[96] = oacc[3][r] * iv;
    }
}

// ================= fallback (round-1 kernel, passes without ws) =================
#define PADK 136
#define PADV 72
#define LDS_SHORTS 31232

__global__ __launch_bounds__(256, 2)
void attn_fwd_fb(const float* __restrict__ Q, const float* __restrict__ K,
                 const float* __restrict__ V, float* __restrict__ O)
{
    __shared__ short lds[LDS_SHORTS];
    short* khi = lds;
    short* klo = lds + 8704;
    short* vt  = lds + 17408;
    short* pls = lds + 26624;

    const int tid  = threadIdx.x;
    const int w    = tid >> 6;
    const int lane = tid & 63;
    const int lg   = lane & 15;
    const int gq   = lane >> 4;
    const int qblk = blockIdx.x;
    const int bh   = blockIdx.y;
    const size_t base = (size_t)bh * S_LEN * D_DIM;
    const int qrow0 = qblk * 64 + w * 16;

    bf8_t qhi[4], qlo[4];
    {
        const float* qp = Q + base + (size_t)(qrow0 + lg) * D_DIM;
        #pragma unroll
        for (int c = 0; c < 4; ++c) {
            const int d0 = c * 32 + gq * 8;
            #pragma unroll
            for (int j = 0; j < 8; ++j) {
                float f = qp[d0 + j];
                short hh = f2bf(f);
                qhi[c][j] = hh;
                qlo[c][j] = f2bf(f - bf2f(hh));
            }
        }
    }

    f32x4 oacc[8];
    #pragma unroll
    for (int n = 0; n < 8; ++n) oacc[n] = (f32x4){0.f, 0.f, 0.f, 0.f};
    float mrow[4] = {-INFINITY, -INFINITY, -INFINITY, -INFINITY};
    float lrow[4] = {0.f, 0.f, 0.f, 0.f};

    for (int kv = 0; kv < S_LEN; kv += 64) {
        __syncthreads();
        {
            const float4* kg = (const float4*)(K + base + (size_t)kv * D_DIM);
            const float4* vg = (const float4*)(V + base + (size_t)kv * D_DIM);
            #pragma unroll
            for (int it = 0; it < 8; ++it) {
                const int f4  = it * 256 + tid;
                const int row = f4 >> 5;
                const int d   = (f4 & 31) * 4;
                float4 kk = kg[f4];
                float4 vv = vg[f4];
                short h0 = f2bf(kk.x), h1 = f2bf(kk.y), h2 = f2bf(kk.z), h3 = f2bf(kk.w);
                short4 hw; hw.x = h0; hw.y = h1; hw.z = h2; hw.w = h3;
                *(short4*)(&khi[row * PADK + d]) = hw;
                short4 lw;
                lw.x = f2bf(kk.x - bf2f(h0));
                lw.y = f2bf(kk.y - bf2f(h1));
                lw.z = f2bf(kk.z - bf2f(h2));
                lw.w = f2bf(kk.w - bf2f(h3));
                *(short4*)(&klo[row * PADK + d]) = lw;
                vt[(d + 0) * PADV + row] = f2bf(vv.x);
                vt[(d + 1) * PADV + row] = f2bf(vv.y);
                vt[(d + 2) * PADV + row] = f2bf(vv.z);
                vt[(d + 3) * PADV + row] = f2bf(vv.w);
            }
        }
        __syncthreads();

        f32x4 sacc[4];
        #pragma unroll
        for (int t = 0; t < 4; ++t) sacc[t] = (f32x4){0.f, 0.f, 0.f, 0.f};
        #pragma unroll
        for (int t = 0; t < 4; ++t) {
            const int krow = t * 16 + lg;
            #pragma unroll
            for (int c = 0; c < 4; ++c) {
                bf8_t kh = *(const bf8_t*)(&khi[krow * PADK + c * 32 + gq * 8]);
                bf8_t kl = *(const bf8_t*)(&klo[krow * PADK + c * 32 + gq * 8]);
                sacc[t] = __builtin_amdgcn_mfma_f32_16x16x32_bf16(qhi[c], kh, sacc[t], 0, 0, 0);
                sacc[t] = __builtin_amdgcn_mfma_f32_16x16x32_bf16(qlo[c], kh, sacc[t], 0, 0, 0);
                sacc[t] = __builtin_amdgcn_mfma_f32_16x16x32_bf16(qhi[c], kl, sacc[t], 0, 0, 0);
            }
        }

        float scl[4];
        #pragma unroll
        for (int r = 0; r < 4; ++r) {
            float tm = fmaxf(fmaxf(sacc[0][r], sacc[1][r]),
                             fmaxf(sacc[2][r], sacc[3][r]));
            #pragma unroll
            for (int off = 8; off >= 1; off >>= 1)
                tm = fmaxf(tm, __shfl_xor(tm, off, 64));
            const float mn = fmaxf(mrow[r], tm);
            const float sc = __expf(mrow[r] - mn);
            float ps = 0.f;
            #pragma unroll
            for (int t = 0; t < 4; ++t) {
                float p = __expf(sacc[t][r] - mn);
                sacc[t][r] = p;
                ps += p;
            }
            #pragma unroll
            for (int off = 8; off >= 1; off >>= 1)
                ps += __shfl_xor(ps, off, 64);
            lrow[r] = lrow[r] * sc + ps;
            mrow[r] = mn;
            scl[r] = sc;
        }
        #pragma unroll
        for (int n = 0; n < 8; ++n) {
            oacc[n][0] *= scl[0];
            oacc[n][1] *= scl[1];
            oacc[n][2] *= scl[2];
            oacc[n][3] *= scl[3];
        }

        short* pw = pls + w * (16 * PADV);
        #pragma unroll
        for (int t = 0; t < 4; ++t)
            #pragma unroll
            for (int r = 0; r < 4; ++r)
                pw[(gq * 4 + r) * PADV + t * 16 + lg] = f2bf(sacc[t][r]);
        asm volatile("s_waitcnt lgkmcnt(0)" ::: "memory");

        #pragma unroll
        for (int kt = 0; kt < 2; ++kt) {
            bf8_t pa = *(const bf8_t*)(&pw[lg * PADV + kt * 32 + gq * 8]);
            #pragma unroll
            for (int n = 0; n < 8; ++n) {
                bf8_t vb = *(const bf8_t*)(&vt[(n * 16 + lg) * PADV + kt * 32 + gq * 8]);
                oacc[n] = __builtin_amdgcn_mfma_f32_16x16x32_bf16(pa, vb, oacc[n], 0, 0, 0);
            }
        }
    }

    float inv[4];
    #pragma unroll
    for (int r = 0; r < 4; ++r) inv[r] = 1.f / lrow[r];
    float* op = O + base + (size_t)qrow0 * D_DIM;
    #pragma unroll
    for (int n = 0; n < 8; ++n)
        #pragma unroll
        for (int r = 0; r < 4; ++r)
            op[(size_t)(gq * 4 + r) * D_DIM + n * 16 + lg] = oacc[n][r] * inv[r];
}

extern "C" void kernel_launch(void* const* d_in, const int* in_sizes, int n_in,
                              void* d_out, int out_size, void* d_ws, size_t ws_size,
                              hipStream_t stream) {
    const float* q = (const float*)d_in[0];
    const float* k = (const float*)d_in[1];
    const float* v = (const float*)d_in[2];
    float* o = (float*)d_out;
    if (ws_size >= (size_t)WS_NEED) {
        char* ws = (char*)d_ws;
        conv_kv<<<2048, 256, 0, stream>>>(k, v, ws, ws + WS_VT);
        attn32<<<512, 512, 0, stream>>>(q, ws, o);
    } else {
        attn_fwd_fb<<<dim3(32, 64), 256, 0, stream>>>(q, k, v, o);
    }
}